// Round 7
// baseline (237.969 us; speedup 1.0000x reference)
//
#include <hip/hip_runtime.h>

// KinematicWaveRouting: outlet(t) = basin_area*50 * sum_k w[k]*runoff(t-k),
// w[k] = P(Binom(k,0.9) <= 19): exactly 1.0 for k<=19 (box part, slid),
// ~10x decay per step after k~21; K=32 taps.
//
// R8 -> R9: R8's counters showed no single saturated resource (HBM 32us eq,
// LDS ~30us eq, VALU 17us eq) yet wall = 78us ~= their SUM: the per-block
// schedule serializes stage-wait -> LDS read -> FMA -> store with only ~6
// resident blocks to overlap. Fix = canonical double-buffered pipeline:
// each block processes 4 tiles (grid 4096, stride 16384 tiles); next tile's
// global loads are ISSUED right after the barrier (into regs), compute of
// the current tile runs from LDS buf[cur] (hiding the load latency), then
// the regs are ds_written into buf[cur^1]. Memory layout, swz, window
// reads, box+weighted FIR, and store pattern are byte-identical to R8.

#define KTAPS 32
#define RPT   8                      // outputs per thread along t
#define TPB   256
#define TILE_T (TPB * RPT)           // 2048 t-values per tile
#define NQ   ((TILE_T + KTAPS) / 4)  // 520 staged quads (16B) incl. 32-halo
#define NBLK 4096                    // grid; each block does n_tiles/NBLK tiles

struct WTab { float w[KTAPS]; };

__device__ __forceinline__ int swz(int q) { return q ^ ((q >> 3) & 7); }

__global__ __launch_bounds__(TPB) void kwr_fir_lds_kernel(
    const float* __restrict__ runoff,
    const float* __restrict__ basin_area,
    float* __restrict__ out,
    int T, int tiles_per_row, int n_tiles, WTab wt)
{
    __shared__ float4 lds[2][NQ];
    const int tid = threadIdx.x;

    float4 st[3];
    int cur = 0;
    int ti = blockIdx.x;

    // ---- prologue: load + stage first tile into buf0 ----------------------
    {
        const int b      = ti / tiles_per_row;
        const int tile   = ti - b * tiles_per_row;
        const int tstart = tile * TILE_T - KTAPS;          // row-local
        const float4* gsrc = (const float4*)(runoff + (long long)b * T + tstart);
        #pragma unroll
        for (int p = 0; p < 3; ++p) {
            int q = tid + p * TPB;
            if (q < NQ)
                st[p] = (tstart + 4 * q >= 0) ? gsrc[q]
                                              : make_float4(0.f, 0.f, 0.f, 0.f);
        }
        #pragma unroll
        for (int p = 0; p < 3; ++p) {
            int q = tid + p * TPB;
            if (q < NQ) lds[0][swz(q)] = st[p];
        }
    }

    for (; ti < n_tiles; ti += NBLK) {
        const int nx = ti + NBLK;
        __syncthreads();                       // buf[cur] visible to all

        // ---- issue next tile's global loads EARLY (hide under compute) ----
        if (nx < n_tiles) {
            const int nb      = nx / tiles_per_row;
            const int ntile   = nx - nb * tiles_per_row;
            const int ntstart = ntile * TILE_T - KTAPS;
            const float4* gsrc =
                (const float4*)(runoff + (long long)nb * T + ntstart);
            #pragma unroll
            for (int p = 0; p < 3; ++p) {
                int q = tid + p * TPB;
                if (q < NQ)
                    st[p] = (ntstart + 4 * q >= 0)
                                ? gsrc[q] : make_float4(0.f, 0.f, 0.f, 0.f);
            }
        }

        // ---- compute current tile from buf[cur] (identical to R8) ---------
        {
            const int b    = ti / tiles_per_row;
            const int tile = ti - b * tiles_per_row;

            float buf[RPT + KTAPS];
            #pragma unroll
            for (int c = 0; c < (RPT + KTAPS) / 4; ++c) {
                float4 v = lds[cur][swz(2 * tid + c)];
                buf[4*c+0] = v.x; buf[4*c+1] = v.y;
                buf[4*c+2] = v.z; buf[4*c+3] = v.w;
            }

            // taps 0..19 == 1.0 exactly: box sum slid across the 8 outputs
            float acc[RPT];
            {
                float S = 0.0f;
                #pragma unroll
                for (int m = 13; m <= 32; ++m) S += buf[m];
                acc[0] = S;
                #pragma unroll
                for (int r = 1; r < RPT; ++r) {
                    S += buf[r + 32] - buf[r + 12];
                    acc[r] = S;
                }
            }
            #pragma unroll
            for (int k = 20; k < KTAPS; ++k) {
                const float wk = wt.w[k];
                #pragma unroll
                for (int r = 0; r < RPT; ++r)
                    acc[r] = fmaf(wk, buf[32 + r - k], acc[r]);
            }

            const float s = basin_area[b] * 50.0f;   // (1e6/1000/3600/20)*DT
            float* orow = out + (long long)b * T + tile * TILE_T + tid * RPT;
            ((float4*)orow)[0] =
                make_float4(acc[0]*s, acc[1]*s, acc[2]*s, acc[3]*s);
            ((float4*)orow)[1] =
                make_float4(acc[4]*s, acc[5]*s, acc[6]*s, acc[7]*s);
        }

        // ---- write the in-flight regs into the other buffer ---------------
        if (nx < n_tiles) {
            #pragma unroll
            for (int p = 0; p < 3; ++p) {
                int q = tid + p * TPB;
                if (q < NQ) lds[cur ^ 1][swz(q)] = st[p];
            }
        }
        cur ^= 1;
    }
}

extern "C" void kernel_launch(void* const* d_in, const int* in_sizes, int n_in,
                              void* d_out, int out_size, void* d_ws, size_t ws_size,
                              hipStream_t stream)
{
    const float* runoff     = (const float*)d_in[0];
    const float* basin_area = (const float*)d_in[1];
    float* out = (float*)d_out;

    const int B = in_sizes[1];            // basin_area has B elements
    const int T = in_sizes[0] / B;        // runoff is (B, T)

    // Impulse response of the linear recurrence, computed in double.
    WTab wt;
    double Q[21];
    for (int j = 0; j <= 20; ++j) Q[j] = (j >= 1) ? 1.0 : 0.0;
    wt.w[0] = 1.0f;
    for (int k = 1; k < KTAPS; ++k) {
        for (int j = 20; j >= 1; --j) Q[j] = 0.1 * Q[j] + 0.9 * Q[j - 1];
        wt.w[k] = (float)Q[20];
    }

    const int tiles_per_row = T / TILE_T;           // 4096 / 2048 = 2
    const int n_tiles = B * tiles_per_row;          // 16384
    const int nblk = (n_tiles < NBLK) ? n_tiles : NBLK;

    kwr_fir_lds_kernel<<<nblk, TPB, 0, stream>>>(runoff, basin_area, out,
                                                 T, tiles_per_row, n_tiles, wt);
}